// Round 3
// baseline (150.022 us; speedup 1.0000x reference)
//
#include <hip/hip_runtime.h>
#include <math.h>

#define B 8
#define IMH 512
#define IMW 512
#define HW (IMH*IMW)
#define NBINS 256

// pyramid per-image: levels 1..4 (256^2, 128^2, 64^2, 32^2)
#define PYR_PER_IMG (65536 + 16384 + 4096 + 1024)   // 87040
#define PYR_OFF_L1 0
#define PYR_OFF_L2 65536
#define PYR_OFF_L3 81920
#define PYR_OFF_L4 86016

#define NTILE 128   // 64x32 tiles per image (8 across x 16 down)

// workspace float-index offsets (all per-block slot arrays, NO atomics anywhere)
#define OFF_PPYR 0
#define OFF_TPYR (B*PYR_PER_IMG)
#define OFF_HISTPART (2*B*PYR_PER_IMG)              // u32: B*NTILE*768 (u16-packed bins)
#define OFF_LABPART  (OFF_HISTPART + B*NTILE*768)   // float: B*NTILE
#define OFF_CSP      (OFF_LABPART + B*NTILE)        // float: B*NTILE (lvl0 cs partials)
#define OFF_LVLS     (OFF_CSP + B*NTILE)            // float: B*85  (lvl1-4 ssim partials)
#define OFF_LVLC     (OFF_LVLS + B*85)              // float: B*85  (lvl1-4 cs partials)
#define OFF_HISTL1   (OFF_LVLC + B*85)              // float: 48    (hist-diff partials)

typedef float f2 __attribute__((ext_vector_type(2)));

__device__ __forceinline__ f2 mkf2(float a, float b) { f2 r; r.x = a; r.y = b; return r; }
__device__ __forceinline__ f2 shfl_down_f2(f2 v, int d) {
    return mkf2(__shfl_down(v.x, d, 64), __shfl_down(v.y, d, 64));
}
__device__ __forceinline__ f2 shfl_f2(f2 v, int src) {
    return mkf2(__shfl(v.x, src, 64), __shfl(v.y, src, 64));
}
__device__ __forceinline__ f2 clamp01_f2(f2 a) {
    a.x = fminf(fmaxf(a.x, 0.0f), 1.0f);
    a.y = fminf(fmaxf(a.y, 0.0f), 1.0f);
    return a;
}

// native exp2/log2 (v_exp_f32 / v_log_f32, <=1 ulp). x must be > 0.
__device__ __forceinline__ float fastpow(float x, float y) {
    return __builtin_amdgcn_exp2f(y * __builtin_amdgcn_logf(x));
}

// packed rgb2lab: component .x = pred, .y = tgt.
__device__ __forceinline__ void rgb2lab_pk(f2 r, f2 g, f2 b, f2 lab[3]) {
    f2 v[3] = {r, g, b};
    f2 lin[3];
    #pragma unroll
    for (int c = 0; c < 3; ++c) {
        f2 x = v[c];
        float hx = fastpow((fmaxf(x.x, 1e-4f) + 0.055f) * (float)(1.0/1.055), 2.4f);
        float hy = fastpow((fmaxf(x.y, 1e-4f) + 0.055f) * (float)(1.0/1.055), 2.4f);
        lin[c].x = (x.x <= 0.04045f) ? x.x * (float)(1.0/12.92) : hx;
        lin[c].y = (x.y <= 0.04045f) ? x.y * (float)(1.0/12.92) : hy;
    }
    f2 X = 0.412453f*lin[0] + 0.357580f*lin[1] + 0.180423f*lin[2];
    f2 Y = 0.212671f*lin[0] + 0.715160f*lin[1] + 0.072169f*lin[2];
    f2 Z = 0.019334f*lin[0] + 0.119193f*lin[1] + 0.950227f*lin[2];
    X = X * (float)(1.0/0.950456);
    Z = Z * (float)(1.0/1.088754);
    const float eps3   = (float)((6.0/29.0)*(6.0/29.0)*(6.0/29.0));
    const float rd3e2  = (float)(1.0/(3.0*(6.0/29.0)*(6.0/29.0)));
    const float c429   = (float)(4.0/29.0);
    f2 xyz[3] = {X, Y, Z};
    f2 f[3];
    #pragma unroll
    for (int c = 0; c < 3; ++c) {
        float ax = xyz[c].x, ay = xyz[c].y;
        f[c].x = (ax <= eps3) ? (ax * rd3e2 + c429) : fastpow(fmaxf(ax, 1e-4f), (float)(1.0/3.0));
        f[c].y = (ay <= eps3) ? (ay * rd3e2 + c429) : fastpow(fmaxf(ay, 1e-4f), (float)(1.0/3.0));
    }
    f2 L  = 116.0f*f[1] - 16.0f;
    f2 A  = 500.0f*f[0] - 500.0f*f[1];
    f2 Bc = 200.0f*f[1] - 200.0f*f[2];
    lab[0] = L * 0.01f;
    lab[1] = (A * (float)(1.0/110.0) + 1.0f) * 0.5f;
    lab[2] = (Bc * (float)(1.0/110.0) + 1.0f) * 0.5f;
}

#define TST 37   // LDS row stride for 36-wide tiles (tail)
#define WT  69   // LDS row stride for 68-wide tiles (main)

// ---- tail conv (36x36 tile, 4 outputs/thread) — unchanged from verified r2 ----
template<bool WANT_S>
__device__ __forceinline__ void conv_ssim(const f2* tile, int t, float& ssum, float& csum) {
    double gd[5]; double gs = 0.0;
    #pragma unroll
    for (int i = 0; i < 5; ++i) { gd[i] = exp(-(double)((i-2)*(i-2)) / 4.5); gs += gd[i]; }
    float gw[5];
    #pragma unroll
    for (int i = 0; i < 5; ++i) gw[i] = (float)(gd[i] / gs);

    int lx = t & 31;
    int yg = t >> 5;

    f2 rA[8], rB[8];
    float r12[8];
    #pragma unroll
    for (int k = 0; k < 8; ++k) {
        int row = yg * 4 + k;
        const f2* p = &tile[row * TST + lx];
        f2 sA = {0.f, 0.f}, sB = {0.f, 0.f};
        float s12 = 0.f;
        #pragma unroll
        for (int dx = 0; dx < 5; ++dx) {
            f2 av = p[dx];
            float wv = gw[dx];
            sA += wv * av;
            f2 sq = av * av;
            sB += wv * sq;
            s12 = fmaf(wv, av.x * av.y, s12);
        }
        rA[k] = sA; rB[k] = sB; r12[k] = s12;
    }

    const float C1 = (float)(0.01 * 0.01);
    const float C2 = (float)(0.03 * 0.03);
    if constexpr (WANT_S) ssum = 0.f;
    csum = 0.f;
    #pragma unroll
    for (int j = 0; j < 4; ++j) {
        f2 mA = {0.f, 0.f}, mB = {0.f, 0.f};
        float m12 = 0.f;
        #pragma unroll
        for (int k = 0; k < 5; ++k) {
            float wv = gw[k];
            mA += wv * rA[j + k];
            mB += wv * rB[j + k];
            m12 = fmaf(wv, r12[j + k], m12);
        }
        float m1 = mA.x, m2 = mA.y;
        float v1  = mB.x - m1 * m1;
        float v2  = mB.y - m2 * m2;
        float v12 = m12 - m1 * m2;
        float n12 = 2.0f * v12 + C2;
        float rd2 = __builtin_amdgcn_rcpf(v1 + v2 + C2);
        csum = fmaf(n12, rd2, csum);
        if constexpr (WANT_S) {
            float rd1 = __builtin_amdgcn_rcpf(m1*m1 + m2*m2 + C1);
            ssum += (2.0f*m1*m2 + C1) * n12 * rd1 * rd2;
        }
    }
}

// ---- main conv (68-wide tile, 64 cols, 8 output rows/thread, rolling 8-slot window) ----
__device__ __forceinline__ void hsum5(const f2* p, const float* gw, f2& A, f2& Bq, float& s12) {
    A = mkf2(0.f, 0.f); Bq = mkf2(0.f, 0.f); s12 = 0.f;
    #pragma unroll
    for (int dx = 0; dx < 5; ++dx) {
        f2 av = p[dx];
        float wv = gw[dx];
        A += wv * av;
        Bq += wv * (av * av);
        s12 = fmaf(wv, av.x * av.y, s12);
    }
}

__device__ __forceinline__ float conv_cs_wide(const f2* tile, int t) {
    double gd[5]; double gs = 0.0;
    #pragma unroll
    for (int i = 0; i < 5; ++i) { gd[i] = exp(-(double)((i-2)*(i-2)) / 4.5); gs += gd[i]; }
    float gw[5];
    #pragma unroll
    for (int i = 0; i < 5; ++i) gw[i] = (float)(gd[i] / gs);

    int x  = t & 63;           // output col
    int R0 = (t >> 6) * 8;     // first output row of this thread's group
    const f2* base = tile + x;

    f2 hA[8], hB[8]; float h12[8];
    #pragma unroll
    for (int k = 0; k < 8; ++k)
        hsum5(base + (R0 + k) * WT, gw, hA[k], hB[k], h12[k]);

    const float C2 = (float)(0.03 * 0.03);
    float csum = 0.f;
    auto emit = [&](int i0, int i1, int i2, int i3, int i4) {
        f2 mA = gw[0]*hA[i0] + gw[1]*hA[i1] + gw[2]*hA[i2] + gw[3]*hA[i3] + gw[4]*hA[i4];
        f2 mB = gw[0]*hB[i0] + gw[1]*hB[i1] + gw[2]*hB[i2] + gw[3]*hB[i3] + gw[4]*hB[i4];
        float m12 = gw[0]*h12[i0] + gw[1]*h12[i1] + gw[2]*h12[i2] + gw[3]*h12[i3] + gw[4]*h12[i4];
        float m1 = mA.x, m2 = mA.y;
        float v1  = mB.x - m1 * m1;
        float v2v = mB.y - m2 * m2;
        float v12 = m12 - m1 * m2;
        csum = fmaf(2.0f * v12 + C2, __builtin_amdgcn_rcpf(v1 + v2v + C2), csum);
    };
    emit(0,1,2,3,4); emit(1,2,3,4,5); emit(2,3,4,5,6); emit(3,4,5,6,7);
    hsum5(base + (R0 +  8) * WT, gw, hA[0], hB[0], h12[0]); emit(4,5,6,7,0);
    hsum5(base + (R0 +  9) * WT, gw, hA[1], hB[1], h12[1]); emit(5,6,7,0,1);
    hsum5(base + (R0 + 10) * WT, gw, hA[2], hB[2], h12[2]); emit(6,7,0,1,2);
    hsum5(base + (R0 + 11) * WT, gw, hA[3], hB[3], h12[3]); emit(7,0,1,2,3);
    return csum;
}

// halo coords for 36x68 padded tile; 400 halo px:
//   [0,136)   top 2 rows x 68
//   [136,272) bottom 2 rows x 68
//   [272,400) middle 32 rows x cols {0,1,66,67}
__device__ __forceinline__ void halo68(int h, int& hr, int& hc) {
    if (h < 136)      { hr = h / 68;            hc = h % 68; }
    else if (h < 272) { int u = h - 136; hr = 34 + u / 68; hc = u % 68; }
    else              { int u = h - 272; hr = 2 + (u >> 2); int q = u & 3; hc = (q < 2) ? q : q + 64; }
}

// Fused: LAB + hist partial + lvl0 SSIM-cs + full pyramid.
// One block = one 64x32 tile, 256 threads, 8 px/thread. grid (128, B).
// NO global atomics: per-block results go to disjoint slots.
__global__ void lab_ssim0_kernel(const float* __restrict__ pred,
                                 const float* __restrict__ tgt,
                                 unsigned* __restrict__ histPart,
                                 float* __restrict__ labPart,
                                 float* __restrict__ csPart,
                                 float* __restrict__ ppyr,
                                 float* __restrict__ tpyr) {
    __shared__ f2 ls[36 * WT];           // packed {Lp, Lt} halo tile (36x68)
    __shared__ unsigned lhist[6 * NBINS];
    __shared__ f2 s1[16 * 32];           // packed L1 (rows x cols)
    __shared__ float red12[12];

    int t  = threadIdx.x;
    int b  = blockIdx.y;
    int bx = blockIdx.x;                 // 0..127

    for (int i = t; i < 6 * NBINS; i += 256) lhist[i] = 0;
    __syncthreads();                                            // B1

    // XCD-aware swizzle: each of 8 XCDs gets a contiguous 2-tile-row strip
    int tile = ((bx & 7) << 4) | (bx >> 3);
    int tx0 = (tile & 7) << 6;           // 0..448 step 64
    int ty0 = (tile >> 3) << 5;          // 0..480 step 32
    int r   = t >> 3;                    // row within tile (0..31)
    int c8  = (t & 7) << 3;              // col within tile (0,8,..,56)
    int gy  = ty0 + r;

    const float* pimg = pred + (size_t)b * 3 * HW;
    const float* timg = tgt  + (size_t)b * 3 * HW;
    size_t ibase = (size_t)gy * IMW + tx0 + c8;

    // ---- issue ALL loads up front: 12x float4 interior + 12 scalar halo ----
    float pr[8], pg[8], pb[8], tr[8], tg[8], tb[8];
    *(float4*)&pr[0] = *(const float4*)(pimg + ibase);
    *(float4*)&pr[4] = *(const float4*)(pimg + ibase + 4);
    *(float4*)&pg[0] = *(const float4*)(pimg + ibase + HW);
    *(float4*)&pg[4] = *(const float4*)(pimg + ibase + HW + 4);
    *(float4*)&pb[0] = *(const float4*)(pimg + ibase + 2*HW);
    *(float4*)&pb[4] = *(const float4*)(pimg + ibase + 2*HW + 4);
    *(float4*)&tr[0] = *(const float4*)(timg + ibase);
    *(float4*)&tr[4] = *(const float4*)(timg + ibase + 4);
    *(float4*)&tg[0] = *(const float4*)(timg + ibase + HW);
    *(float4*)&tg[4] = *(const float4*)(timg + ibase + HW + 4);
    *(float4*)&tb[0] = *(const float4*)(timg + ibase + 2*HW);
    *(float4*)&tb[4] = *(const float4*)(timg + ibase + 2*HW + 4);

    int hrA, hcA; halo68(t, hrA, hcA);
    int hyA = ty0 - 2 + hrA, hxA = tx0 - 2 + hcA;
    bool hvA = ((unsigned)hyA < 512u) && ((unsigned)hxA < 512u);
    size_t hoA = hvA ? ((size_t)hyA * IMW + hxA) : 0;
    float aPr = pimg[hoA], aPg = pimg[hoA + HW], aPb = pimg[hoA + 2*HW];
    float aTr = timg[hoA], aTg = timg[hoA + HW], aTb = timg[hoA + 2*HW];

    bool hasB = t < 144;                 // 400 - 256
    int hrB, hcB; halo68(hasB ? (256 + t) : 0, hrB, hcB);
    int hyB = ty0 - 2 + hrB, hxB = tx0 - 2 + hcB;
    bool hvB = hasB && ((unsigned)hyB < 512u) && ((unsigned)hxB < 512u);
    size_t hoB = hvB ? ((size_t)hyB * IMW + hxB) : 0;
    float bPr = pimg[hoB], bPg = pimg[hoB + HW], bPb = pimg[hoB + 2*HW];
    float bTr = timg[hoB], bTg = timg[hoB + HW], bTb = timg[hoB + 2*HW];

    // ---- interior compute: 8 independent px chains (halo loads in flight) ----
    float l1 = 0.0f;
    f2 pL[8];
    #pragma unroll
    for (int k = 0; k < 8; ++k) {
        f2 lab[3];
        rgb2lab_pk(mkf2(pr[k], tr[k]), mkf2(pg[k], tg[k]), mkf2(pb[k], tb[k]), lab);
        #pragma unroll
        for (int c = 0; c < 3; ++c) {
            f2 lc = clamp01_f2(lab[c]);
            l1 += fabsf(lc.x - lc.y);
            int ip = min(max((int)floorf(lc.x * (float)NBINS), 0), NBINS - 1);
            int it = min(max((int)floorf(lc.y * (float)NBINS), 0), NBINS - 1);
            atomicAdd(&lhist[c * NBINS + ip], 1u);
            atomicAdd(&lhist[(3 + c) * NBINS + it], 1u);
            if (c == 0) pL[k] = lc;
        }
        ls[(r + 2) * WT + (c8 + 2 + k)] = pL[k];
    }

    // ---- pyramid L1 (pre-barrier: intra-wave shuffles + s1/global stores) ----
    float* pyrP = ppyr + (size_t)b * PYR_PER_IMG;
    float* pyrT = tpyr + (size_t)b * PYR_PER_IMG;
    {
        f2 ph[4];
        ph[0] = pL[0] + pL[1]; ph[1] = pL[2] + pL[3];
        ph[2] = pL[4] + pL[5]; ph[3] = pL[6] + pL[7];
        f2 pv[4];
        #pragma unroll
        for (int j = 0; j < 4; ++j) pv[j] = shfl_down_f2(ph[j], 8);   // row r+1, same cols
        if ((t & 8) == 0) {              // even row r
            int y1 = r >> 1;             // 0..15
            int x1 = (t & 7) << 2;       // 0..28 step 4
            f2 w0 = 0.25f * (ph[0] + pv[0]);
            f2 w1 = 0.25f * (ph[1] + pv[1]);
            f2 w2 = 0.25f * (ph[2] + pv[2]);
            f2 w3 = 0.25f * (ph[3] + pv[3]);
            s1[y1 * 32 + x1 + 0] = w0;
            s1[y1 * 32 + x1 + 1] = w1;
            s1[y1 * 32 + x1 + 2] = w2;
            s1[y1 * 32 + x1 + 3] = w3;
            int g1 = ((ty0 >> 1) + y1) * 256 + (tx0 >> 1) + x1;
            *(float4*)&pyrP[PYR_OFF_L1 + g1] = make_float4(w0.x, w1.x, w2.x, w3.x);
            *(float4*)&pyrT[PYR_OFF_L1 + g1] = make_float4(w0.y, w1.y, w2.y, w3.y);
        }
    }

    // ---- halo px A (prefetched) ----
    {
        f2 lab[3];
        rgb2lab_pk(mkf2(aPr, aTr), mkf2(aPg, aTg), mkf2(aPb, aTb), lab);
        f2 Lv = hvA ? clamp01_f2(lab[0]) : mkf2(0.f, 0.f);
        ls[hrA * WT + hcA] = Lv;
    }
    // ---- halo px B (t < 144) ----
    if (hasB) {
        f2 lab[3];
        rgb2lab_pk(mkf2(bPr, bTr), mkf2(bPg, bTg), mkf2(bPb, bTb), lab);
        f2 Lv = hvB ? clamp01_f2(lab[0]) : mkf2(0.f, 0.f);
        ls[hrB * WT + hcB] = Lv;
    }
    __syncthreads();                                            // B2

    // non-atomic per-block histogram partial, u16-packed two bins per u32
    unsigned* hp = histPart + ((size_t)b * NTILE + bx) * 768;
    for (int i = t; i < 768; i += 256)
        hp[i] = (lhist[2*i] & 0xFFFFu) | (lhist[2*i + 1] << 16);

    // lvl0 SSIM-cs from packed LDS tile (8 output rows/thread)
    float csum = conv_cs_wide(ls, t);

    // pyramid L2-L4: waves 0,1 (shuffle cascade, no extra barriers)
    if (t < 128) {
        int y2 = t >> 4, x2 = t & 15;                   // L2 tile 8x16
        const f2* s = &s1[(2*y2) * 32 + 2*x2];
        f2 v2 = 0.25f * (s[0] + s[1] + s[32] + s[33]);
        int g2 = ((ty0 >> 2) + y2) * 128 + (tx0 >> 2) + x2;
        pyrP[PYR_OFF_L2 + g2] = v2.x;
        pyrT[PYR_OFF_L2 + g2] = v2.y;

        int w = t >> 6;                                 // wave id 0/1 (rows y2: 4w..4w+3)
        int l = t & 63;
        int y3l = (l >> 3) & 1, x3 = l & 7;
        f2 v3 = 0.25f * (shfl_f2(v2, 32*y3l + 2*x3)      + shfl_f2(v2, 32*y3l + 2*x3 + 1) +
                         shfl_f2(v2, 32*y3l + 16 + 2*x3) + shfl_f2(v2, 32*y3l + 17 + 2*x3));
        if (l < 16) {                                   // L3 tile 4x8: rows 2w+y3l
            int g3 = ((ty0 >> 3) + 2*w + y3l) * 64 + (tx0 >> 3) + x3;
            pyrP[PYR_OFF_L3 + g3] = v3.x;
            pyrT[PYR_OFF_L3 + g3] = v3.y;
        }
        int x4 = l & 3;
        f2 v4 = 0.25f * (shfl_f2(v3, 2*x4)     + shfl_f2(v3, 2*x4 + 1) +
                         shfl_f2(v3, 8 + 2*x4) + shfl_f2(v3, 9 + 2*x4));
        if (l < 4) {                                    // L4 tile 2x4: row w
            int g4 = ((ty0 >> 4) + w) * 32 + (tx0 >> 4) + x4;
            pyrP[PYR_OFF_L4 + g4] = v4.x;
            pyrT[PYR_OFF_L4 + g4] = v4.y;
        }
    }

    // combined reduction: l1, csum -> per-block slots (no atomics)
    int lane = t & 63;
    int wid  = t >> 6;
    #pragma unroll
    for (int o = 32; o >= 1; o >>= 1) {
        l1   += __shfl_down(l1, o, 64);
        csum += __shfl_down(csum, o, 64);
    }
    if (lane == 0) {
        red12[wid * 2 + 0] = l1;
        red12[wid * 2 + 1] = csum;
    }
    __syncthreads();                                            // B3
    if (t < 4) {
        float a0 = red12[t * 2 + 0];
        float a2 = red12[t * 2 + 1];
        #pragma unroll
        for (int o = 2; o >= 1; o >>= 1) {
            a0 += __shfl_down(a0, o, 64);
            a2 += __shfl_down(a2, o, 64);
        }
        if (t == 0) {
            labPart[b * NTILE + bx] = a0;
            csPart[b * NTILE + bx]  = a2;
        }
    }
}

// Tail: 728 blocks, NO atomics / fences / counters — per-block slot writes only.
//   bx < 48           : hist partial reduce — 6 blocks/image, 64 words each
//   48 <= bx < 728    : SSIM levels 1-4 (85 per image)
__global__ void tail_kernel(const float* __restrict__ ppyr,
                            const float* __restrict__ tpyr,
                            const unsigned* __restrict__ histPart,
                            float* __restrict__ lvlS,
                            float* __restrict__ lvlC,
                            float* __restrict__ histL1p) {
    __shared__ f2 tls[36 * TST];
    __shared__ float red12[12];
    __shared__ int dLo[256];
    __shared__ int dHi[256];
    int t = threadIdx.x;
    int bx = blockIdx.x;

    if (bx < 48) {
        int b  = bx / 6;                       // image
        int w  = (bx % 6) * 64 + (t & 63);     // packed word within image (0..383)
        int ck = t >> 6;                       // tile chunk 0..3 (32 tiles each)
        const unsigned* p = histPart + (size_t)b * NTILE * 768 + (size_t)(ck * 32) * 768;
        unsigned sPlo = 0, sPhi = 0, sTlo = 0, sThi = 0;
        #pragma unroll 8
        for (int i = 0; i < 32; ++i) {
            unsigned wP = p[(size_t)i * 768 + w];          // lanes contiguous
            unsigned wT = p[(size_t)i * 768 + 384 + w];
            sPlo += wP & 0xFFFFu;  sPhi += wP >> 16;
            sTlo += wT & 0xFFFFu;  sThi += wT >> 16;
        }
        dLo[t] = (int)sPlo - (int)sTlo;        // exact signed partial diffs
        dHi[t] = (int)sPhi - (int)sThi;
        __syncthreads();
        if (t < 64) {                          // wave 0: combine 4 chunks per word
            int lo = dLo[t] + dLo[t + 64] + dLo[t + 128] + dLo[t + 192];
            int hi = dHi[t] + dHi[t + 64] + dHi[t + 128] + dHi[t + 192];
            float val = fabsf((float)lo) + fabsf((float)hi);   // exact: |.| < 2^24
            #pragma unroll
            for (int o = 32; o >= 1; o >>= 1) val += __shfl_down(val, o, 64);
            if (t == 0) histL1p[bx] = val;     // slot write, no atomic
        }
    } else {
        int cb = bx - 48;
        int b = cb / 85;
        int sub = cb - b * 85;
        int lvl, pblk;
        if (sub < 64)      { lvl = 1; pblk = sub; }
        else if (sub < 80) { lvl = 2; pblk = sub - 64; }
        else if (sub < 84) { lvl = 3; pblk = sub - 80; }
        else               { lvl = 4; pblk = 0; }

        const int offs[5] = {0, PYR_OFF_L1, PYR_OFF_L2, PYR_OFF_L3, PYR_OFF_L4};
        int w = 512 >> lvl;
        const float* i1 = ppyr + (size_t)b * PYR_PER_IMG + offs[lvl];
        const float* i2 = tpyr + (size_t)b * PYR_PER_IMG + offs[lvl];

        int tprShift = 4 - lvl;
        int ty0 = (pblk >> tprShift) << 5;
        int tx0 = (pblk & ((1 << tprShift) - 1)) << 5;

        for (int i = t; i < 36 * 36; i += 256) {
            int r = i / 36, c = i % 36;
            int gy = ty0 - 2 + r;
            int gx = tx0 - 2 + c;
            bool ok = ((unsigned)gy < (unsigned)w) && ((unsigned)gx < (unsigned)w);
            int gi = gy * w + gx;
            tls[r * TST + c] = ok ? mkf2(i1[gi], i2[gi]) : mkf2(0.f, 0.f);
        }
        __syncthreads();

        float ssum, csum;
        conv_ssim<true>(tls, t, ssum, csum);

        int lane = t & 63;
        int wid  = t >> 6;
        #pragma unroll
        for (int o = 32; o >= 1; o >>= 1) {
            ssum += __shfl_down(ssum, o, 64);
            csum += __shfl_down(csum, o, 64);
        }
        if (lane == 0) {
            red12[wid * 2 + 0] = ssum;
            red12[wid * 2 + 1] = csum;
        }
        __syncthreads();
        if (t < 4) {
            float a1 = red12[t * 2 + 0];
            float a2 = red12[t * 2 + 1];
            #pragma unroll
            for (int o = 2; o >= 1; o >>= 1) {
                a1 += __shfl_down(a1, o, 64);
                a2 += __shfl_down(a2, o, 64);
            }
            if (t == 0) {
                lvlS[cb] = a1;                 // slot writes, no atomics
                lvlC[cb] = a2;
            }
        }
    }
}

// Final: ONE block does all the tiny reductions + output math.
__global__ void final_kernel(const float* __restrict__ labPart,
                             const float* __restrict__ csPart,
                             const float* __restrict__ lvlS,
                             const float* __restrict__ lvlC,
                             const float* __restrict__ histL1p,
                             float* __restrict__ out) {
    // sh layout (doubles): [0,8) cs lvl0 per image; [8,16) cs lvl1; [16,24) cs lvl2;
    //                      [24,32) cs lvl3; [32,40) ssim lvl4; [40,48) hist per image
    __shared__ double sh[48];
    __shared__ double wred[4];
    int t = threadIdx.x;

    // per-image lvl0 cs: 32 lanes per image, 4 slots each (NTILE=128)
    {
        int b = t >> 5, k = t & 31;
        double s = 0.0;
        #pragma unroll
        for (int j = 0; j < 4; ++j) s += (double)csPart[b * NTILE + k + 32 * j];
        #pragma unroll
        for (int o = 16; o >= 1; o >>= 1) s += __shfl_down(s, o, 32);
        if (k == 0) sh[b] = s;
    }
    // lab total over all B*NTILE = 1024 slots
    {
        double s = 0.0;
        #pragma unroll
        for (int j = 0; j < 4; ++j) s += (double)labPart[t + 256 * j];
        #pragma unroll
        for (int o = 32; o >= 1; o >>= 1) s += __shfl_down(s, o, 64);
        if ((t & 63) == 0) wred[t >> 6] = s;
    }
    // level sums: t<32 -> b=t>>2, q=t&3; q=0..2: cs lvl(q+1); q=3: ssim lvl4
    if (t < 32) {
        int b = t >> 2, q = t & 3;
        const int lo[4] = {0, 64, 80, 84};
        const int hi[4] = {64, 80, 84, 85};
        const float* src = (q == 3) ? lvlS : lvlC;
        double s = 0.0;
        for (int i = lo[q]; i < hi[q]; ++i) s += (double)src[b * 85 + i];
        sh[8 + q * 8 + b] = s;
    }
    // hist per image: 6 slots each
    if (t < 8) {
        double s = 0.0;
        #pragma unroll
        for (int j = 0; j < 6; ++j) s += (double)histL1p[t * 6 + j];
        sh[40 + t] = s;
    }
    __syncthreads();

    if (t < 8) {
        const float msw[5]  = {0.0448f, 0.2856f, 0.3001f, 0.2363f, 0.1333f};
        const float npix[5] = {(float)HW, (float)(HW/4), (float)(HW/16),
                               (float)(HW/64), (float)(HW/256)};
        int b = t;
        float l1 = (float)(sh[40 + b] / (double)(3 * NBINS));
        float wgt = __builtin_amdgcn_exp2f((float)(b - B));   // 2^(b-8), exact
        float histc = wgt * (l1 + 1.0f);
        float ms = 1.0f;
        float cs0 = (float)(sh[b] / (double)npix[0]);
        ms *= fastpow((cs0 + 1.0f) * 0.5f, msw[0]);
        #pragma unroll
        for (int l = 1; l <= 3; ++l) {
            float cs = (float)(sh[l * 8 + b] / (double)npix[l]);
            ms *= fastpow((cs + 1.0f) * 0.5f, msw[l]);
        }
        float sm = (float)(sh[32 + b] / (double)npix[4]);
        ms *= fastpow((sm + 1.0f) * 0.5f, msw[4]);
        float lossc = 1.0f - ms;
        #pragma unroll
        for (int o = 4; o >= 1; o >>= 1) {
            histc += __shfl_down(histc, o, 64);
            lossc += __shfl_down(lossc, o, 64);
        }
        if (t == 0) {
            double labSum = wred[0] + wred[1] + wred[2] + wred[3];
            float scaler = (float)HW / 20.0f;
            float hist_loss = histc / (float)B / scaler;
            float lab_l1 = (float)(labSum / (double)((size_t)B * 3 * HW));
            out[0] = lab_l1 + hist_loss;
            out[1] = lossc / (float)B;
        }
    }
}

extern "C" void kernel_launch(void* const* d_in, const int* in_sizes, int n_in,
                              void* d_out, int out_size, void* d_ws, size_t ws_size,
                              hipStream_t stream) {
    const float* pred = (const float*)d_in[1];
    const float* tgt  = (const float*)d_in[2];
    float* ws_f = (float*)d_ws;

    float* ppyr     = ws_f + OFF_PPYR;
    float* tpyr     = ws_f + OFF_TPYR;
    unsigned* histPart = (unsigned*)(ws_f + OFF_HISTPART);
    float* labPart  = ws_f + OFF_LABPART;
    float* csPart   = ws_f + OFF_CSP;
    float* lvlS     = ws_f + OFF_LVLS;
    float* lvlC     = ws_f + OFF_LVLC;
    float* histL1p  = ws_f + OFF_HISTL1;
    float* out = (float*)d_out;

    // no memset needed: every workspace slot is fully rewritten before being read

    lab_ssim0_kernel<<<dim3(NTILE, B), 256, 0, stream>>>(pred, tgt, histPart, labPart,
                                                         csPart, ppyr, tpyr);

    tail_kernel<<<728, 256, 0, stream>>>(ppyr, tpyr, histPart, lvlS, lvlC, histL1p);

    final_kernel<<<1, 256, 0, stream>>>(labPart, csPart, lvlS, lvlC, histL1p, out);
}

// Round 4
// 143.815 us; speedup vs baseline: 1.0432x; 1.0432x over previous
//
#include <hip/hip_runtime.h>
#include <math.h>

#define B 8
#define IMH 512
#define IMW 512
#define HW (IMH*IMW)
#define NBINS 256

// pyramid per-image: levels 1..4 (256^2, 128^2, 64^2, 32^2)
#define PYR_PER_IMG (65536 + 16384 + 4096 + 1024)   // 87040
#define PYR_OFF_L1 0
#define PYR_OFF_L2 65536
#define PYR_OFF_L3 81920
#define PYR_OFF_L4 86016

// workspace float-index offsets (per-block slot arrays; only atomic = completion counter)
#define OFF_PPYR 0
#define OFF_TPYR (B*PYR_PER_IMG)
#define OFF_HISTPART (2*B*PYR_PER_IMG)              // u32: B*256*768 (u16-packed bins)
#define OFF_LABPART  (OFF_HISTPART + B*256*768)     // float: B*256
#define OFF_CSP      (OFF_LABPART + B*256)          // float: B*256 (lvl0 cs partials)
#define OFF_LVLS     (OFF_CSP + B*256)              // float: B*85  (lvl1-4 ssim partials)
#define OFF_LVLC     (OFF_LVLS + B*85)              // float: B*85  (lvl1-4 cs partials)
#define OFF_HISTL1   (OFF_LVLC + B*85)              // float: 48    (hist-diff partials)
#define OFF_CNT      (OFF_HISTL1 + 48)              // u32: completion counter

typedef float f2 __attribute__((ext_vector_type(2)));

__device__ __forceinline__ f2 mkf2(float a, float b) { f2 r; r.x = a; r.y = b; return r; }
__device__ __forceinline__ f2 shfl_down_f2(f2 v, int d) {
    return mkf2(__shfl_down(v.x, d, 64), __shfl_down(v.y, d, 64));
}
__device__ __forceinline__ f2 shfl_f2(f2 v, int src) {
    return mkf2(__shfl(v.x, src, 64), __shfl(v.y, src, 64));
}
__device__ __forceinline__ f2 clamp01_f2(f2 a) {
    a.x = fminf(fmaxf(a.x, 0.0f), 1.0f);
    a.y = fminf(fmaxf(a.y, 0.0f), 1.0f);
    return a;
}

// device-scope (cross-XCD coherent) float load for the last-block finish
__device__ __forceinline__ float aload(const float* p) {
    return __hip_atomic_load(p, __ATOMIC_RELAXED, __HIP_MEMORY_SCOPE_AGENT);
}

// native exp2/log2 (v_exp_f32 / v_log_f32, <=1 ulp). x must be > 0.
__device__ __forceinline__ float fastpow(float x, float y) {
    return __builtin_amdgcn_exp2f(y * __builtin_amdgcn_logf(x));
}

// packed rgb2lab: component .x = pred, .y = tgt.
__device__ __forceinline__ void rgb2lab_pk(f2 r, f2 g, f2 b, f2 lab[3]) {
    f2 v[3] = {r, g, b};
    f2 lin[3];
    #pragma unroll
    for (int c = 0; c < 3; ++c) {
        f2 x = v[c];
        float hx = fastpow((fmaxf(x.x, 1e-4f) + 0.055f) * (float)(1.0/1.055), 2.4f);
        float hy = fastpow((fmaxf(x.y, 1e-4f) + 0.055f) * (float)(1.0/1.055), 2.4f);
        lin[c].x = (x.x <= 0.04045f) ? x.x * (float)(1.0/12.92) : hx;
        lin[c].y = (x.y <= 0.04045f) ? x.y * (float)(1.0/12.92) : hy;
    }
    f2 X = 0.412453f*lin[0] + 0.357580f*lin[1] + 0.180423f*lin[2];
    f2 Y = 0.212671f*lin[0] + 0.715160f*lin[1] + 0.072169f*lin[2];
    f2 Z = 0.019334f*lin[0] + 0.119193f*lin[1] + 0.950227f*lin[2];
    X = X * (float)(1.0/0.950456);
    Z = Z * (float)(1.0/1.088754);
    const float eps3   = (float)((6.0/29.0)*(6.0/29.0)*(6.0/29.0));
    const float rd3e2  = (float)(1.0/(3.0*(6.0/29.0)*(6.0/29.0)));
    const float c429   = (float)(4.0/29.0);
    f2 xyz[3] = {X, Y, Z};
    f2 f[3];
    #pragma unroll
    for (int c = 0; c < 3; ++c) {
        float ax = xyz[c].x, ay = xyz[c].y;
        f[c].x = (ax <= eps3) ? (ax * rd3e2 + c429) : fastpow(fmaxf(ax, 1e-4f), (float)(1.0/3.0));
        f[c].y = (ay <= eps3) ? (ay * rd3e2 + c429) : fastpow(fmaxf(ay, 1e-4f), (float)(1.0/3.0));
    }
    f2 L  = 116.0f*f[1] - 16.0f;
    f2 A  = 500.0f*f[0] - 500.0f*f[1];
    f2 Bc = 200.0f*f[1] - 200.0f*f[2];
    lab[0] = L * 0.01f;
    lab[1] = (A * (float)(1.0/110.0) + 1.0f) * 0.5f;
    lab[2] = (Bc * (float)(1.0/110.0) + 1.0f) * 0.5f;
}

#define TST 37   // LDS row stride for 36-wide tiles

// packed separable 5x5 Gaussian SSIM over a 36x36 f2 tile ({pred,tgt} interleaved).
// v_rcp_f32 instead of precise div (rel err ~1e-7, threshold 7e-3).
// WANT_S=false skips the ssim-map sum (only mcs[0..3] and mssim[4] reach the output).
template<bool WANT_S>
__device__ __forceinline__ void conv_ssim(const f2* tile, int t, float& ssum, float& csum) {
    double gd[5]; double gs = 0.0;
    #pragma unroll
    for (int i = 0; i < 5; ++i) { gd[i] = exp(-(double)((i-2)*(i-2)) / 4.5); gs += gd[i]; }
    float gw[5];
    #pragma unroll
    for (int i = 0; i < 5; ++i) gw[i] = (float)(gd[i] / gs);

    int lx = t & 31;
    int yg = t >> 5;

    f2 rA[8], rB[8];     // {m1,m2}, {m11,m22}
    float r12[8];
    #pragma unroll
    for (int k = 0; k < 8; ++k) {
        int row = yg * 4 + k;
        const f2* p = &tile[row * TST + lx];
        f2 sA = {0.f, 0.f}, sB = {0.f, 0.f};
        float s12 = 0.f;
        #pragma unroll
        for (int dx = 0; dx < 5; ++dx) {
            f2 av = p[dx];
            float wv = gw[dx];
            sA += wv * av;
            f2 sq = av * av;
            sB += wv * sq;
            s12 = fmaf(wv, av.x * av.y, s12);
        }
        rA[k] = sA; rB[k] = sB; r12[k] = s12;
    }

    const float C1 = (float)(0.01 * 0.01);
    const float C2 = (float)(0.03 * 0.03);
    if constexpr (WANT_S) ssum = 0.f;
    csum = 0.f;
    #pragma unroll
    for (int j = 0; j < 4; ++j) {
        f2 mA = {0.f, 0.f}, mB = {0.f, 0.f};
        float m12 = 0.f;
        #pragma unroll
        for (int k = 0; k < 5; ++k) {
            float wv = gw[k];
            mA += wv * rA[j + k];
            mB += wv * rB[j + k];
            m12 = fmaf(wv, r12[j + k], m12);
        }
        float m1 = mA.x, m2 = mA.y;
        float v1  = mB.x - m1 * m1;
        float v2  = mB.y - m2 * m2;
        float v12 = m12 - m1 * m2;
        float n12 = 2.0f * v12 + C2;
        float rd2 = __builtin_amdgcn_rcpf(v1 + v2 + C2);
        csum = fmaf(n12, rd2, csum);
        if constexpr (WANT_S) {
            float rd1 = __builtin_amdgcn_rcpf(m1*m1 + m2*m2 + C1);
            ssum += (2.0f*m1*m2 + C1) * n12 * rd1 * rd2;
        }
    }
}

__device__ __forceinline__ void halo_coords(int h, int& hr, int& hc) {
    if (h < 72)       { hr = h / 36;            hc = h % 36; }
    else if (h < 144) { int u = h - 72;  hr = 34 + u / 36; hc = u % 36; }
    else              { int u = h - 144; hr = 2 + (u >> 2); int q = u & 3; hc = (q < 2) ? q : 32 + q; }
}

// Fused: LAB + hist partial + lvl0 SSIM-cs (halo recompute, prefetched) + full pyramid.
// One block = one 32x32 tile. grid (256, B) x 256; 4 px/thread.  [r2-verified structure]
__global__ void lab_ssim0_kernel(const float* __restrict__ pred,
                                 const float* __restrict__ tgt,
                                 unsigned* __restrict__ histPart,
                                 float* __restrict__ labPart,
                                 float* __restrict__ csPart,
                                 float* __restrict__ ppyr,
                                 float* __restrict__ tpyr,
                                 unsigned* __restrict__ counter) {
    __shared__ f2 ls[36 * TST];          // packed {Lp, Lt} halo tile
    __shared__ unsigned lhist[6 * NBINS];
    __shared__ f2 s1[16 * 16];           // packed L1
    __shared__ float red12[12];

    int t  = threadIdx.x;
    int b  = blockIdx.y;
    int bx = blockIdx.x;

    // zero the tail's completion counter (workspace is re-poisoned every iteration);
    // visible to tail_kernel at kernel boundary (same stream)
    if (b == 0 && bx == 0 && t == 0) *counter = 0u;

    for (int i = t; i < 6 * NBINS; i += 256) lhist[i] = 0;
    __syncthreads();                                            // B1

    // XCD-aware swizzle: consecutive dispatch ids -> disjoint 2-tile-row strips
    int tile = ((bx & 7) << 5) | (bx >> 3);
    int tx0 = (tile & 15) << 5;
    int ty0 = (tile >> 4) << 5;
    int r   = t >> 3;            // row within tile (0..31)
    int c4  = (t & 7) << 2;      // col within tile (0,4,..,28)
    int gy  = ty0 + r;

    const float* pimg = pred + (size_t)b * 3 * HW;
    const float* timg = tgt  + (size_t)b * 3 * HW;
    size_t ibase = (size_t)gy * IMW + tx0 + c4;

    // ---- issue ALL loads up front (interior 6x float4 + halo px t's 6 scalars) ----
    float prA[4], pgA[4], pbA[4], trA[4], tgA[4], tbA[4];
    *(float4*)&prA[0] = *(const float4*)(pimg + ibase);
    *(float4*)&pgA[0] = *(const float4*)(pimg + ibase + HW);
    *(float4*)&pbA[0] = *(const float4*)(pimg + ibase + 2*HW);
    *(float4*)&trA[0] = *(const float4*)(timg + ibase);
    *(float4*)&tgA[0] = *(const float4*)(timg + ibase + HW);
    *(float4*)&tbA[0] = *(const float4*)(timg + ibase + 2*HW);

    int hr0, hc0;
    halo_coords(t, hr0, hc0);
    int hy0 = ty0 - 2 + hr0;
    int hx0 = tx0 - 2 + hc0;
    bool hv0 = ((unsigned)hy0 < 512u) && ((unsigned)hx0 < 512u);
    size_t ho = hv0 ? ((size_t)hy0 * IMW + hx0) : 0;   // clamped addr, masked later
    float h_pr = pimg[ho], h_pg = pimg[ho + HW], h_pb = pimg[ho + 2*HW];
    float h_tr = timg[ho], h_tg = timg[ho + HW], h_tb = timg[ho + 2*HW];

    // ---- interior compute (halo loads in flight) ----
    float l1 = 0.0f;
    f2 pL[4];
    #pragma unroll
    for (int k = 0; k < 4; ++k) {
        f2 lab[3];
        rgb2lab_pk(mkf2(prA[k], trA[k]), mkf2(pgA[k], tgA[k]), mkf2(pbA[k], tbA[k]), lab);
        #pragma unroll
        for (int c = 0; c < 3; ++c) {
            f2 lc = clamp01_f2(lab[c]);
            l1 += fabsf(lc.x - lc.y);
            int ip = min(max((int)floorf(lc.x * (float)NBINS), 0), NBINS - 1);
            int it = min(max((int)floorf(lc.y * (float)NBINS), 0), NBINS - 1);
            atomicAdd(&lhist[c * NBINS + ip], 1u);
            atomicAdd(&lhist[(3 + c) * NBINS + it], 1u);
            if (c == 0) pL[k] = lc;
        }
        ls[(r + 2) * TST + (c4 + 2 + k)] = pL[k];
    }

    // ---- halo px t (prefetched) ----
    {
        f2 lab[3];
        rgb2lab_pk(mkf2(h_pr, h_tr), mkf2(h_pg, h_tg), mkf2(h_pb, h_tb), lab);
        f2 Lv = hv0 ? clamp01_f2(lab[0]) : mkf2(0.f, 0.f);
        ls[hr0 * TST + hc0] = Lv;
    }
    // ---- remaining 16 halo px (t < 16) ----
    if (t < 16) {
        int hr, hc;
        halo_coords(256 + t, hr, hc);
        int hy = ty0 - 2 + hr;
        int hx = tx0 - 2 + hc;
        f2 Lv = {0.f, 0.f};
        if ((unsigned)hy < 512u && (unsigned)hx < 512u) {
            size_t o = (size_t)hy * IMW + hx;
            f2 lab[3];
            rgb2lab_pk(mkf2(pimg[o], timg[o]),
                       mkf2(pimg[o + HW], timg[o + HW]),
                       mkf2(pimg[o + 2*HW], timg[o + 2*HW]), lab);
            Lv = clamp01_f2(lab[0]);
        }
        ls[hr * TST + hc] = Lv;
    }
    __syncthreads();                                            // B2

    // non-atomic per-block histogram partial, u16-packed two bins per u32
    unsigned* hp = histPart + ((size_t)b * 256 + bx) * 768;
    for (int i = t; i < 768; i += 256)
        hp[i] = (lhist[2*i] & 0xFFFFu) | (lhist[2*i + 1] << 16);

    // pyramid L1 from registers (shuffles), packed
    float* pyrP = ppyr + (size_t)b * PYR_PER_IMG;
    float* pyrT = tpyr + (size_t)b * PYR_PER_IMG;
    f2 ph0 = pL[0] + pL[1], ph1 = pL[2] + pL[3];
    f2 ph0b = shfl_down_f2(ph0, 8);
    f2 ph1b = shfl_down_f2(ph1, 8);
    if ((t & 8) == 0) {                 // even row r
        int y1 = r >> 1;
        int x1 = (t & 7) << 1;
        f2 v0 = 0.25f * (ph0 + ph0b);
        f2 v1 = 0.25f * (ph1 + ph1b);
        s1[y1 * 16 + x1]     = v0;
        s1[y1 * 16 + x1 + 1] = v1;
        int g1 = ((ty0 >> 1) + y1) * 256 + (tx0 >> 1) + x1;
        *(float2*)&pyrP[PYR_OFF_L1 + g1] = make_float2(v0.x, v1.x);
        *(float2*)&pyrT[PYR_OFF_L1 + g1] = make_float2(v0.y, v1.y);
    }
    __syncthreads();                                            // B3

    // lvl0 SSIM-cs from packed LDS tile (ssim-map sum not needed at lvl0)
    float sdummy, csum;
    conv_ssim<false>(ls, t, sdummy, csum);

    // pyramid L2-L4: wave 0 only (shuffle cascade, no barriers)
    if (t < 64) {
        int y2 = t >> 3, x2 = t & 7;
        const f2* s = &s1[(2*y2) * 16 + 2*x2];
        f2 v2 = 0.25f * (s[0] + s[1] + s[16] + s[17]);
        pyrP[PYR_OFF_L2 + ((ty0 >> 2) + y2) * 128 + (tx0 >> 2) + x2] = v2.x;
        pyrT[PYR_OFF_L2 + ((ty0 >> 2) + y2) * 128 + (tx0 >> 2) + x2] = v2.y;

        int y3 = (t >> 2) & 3, x3 = t & 3;
        f2 v3 = 0.25f * (shfl_f2(v2, (2*y3)*8 + 2*x3)     + shfl_f2(v2, (2*y3)*8 + 2*x3 + 1) +
                         shfl_f2(v2, (2*y3+1)*8 + 2*x3)   + shfl_f2(v2, (2*y3+1)*8 + 2*x3 + 1));
        if (t < 16) {
            pyrP[PYR_OFF_L3 + ((ty0 >> 3) + y3) * 64 + (tx0 >> 3) + x3] = v3.x;
            pyrT[PYR_OFF_L3 + ((ty0 >> 3) + y3) * 64 + (tx0 >> 3) + x3] = v3.y;
        }
        int y4 = (t >> 1) & 1, x4 = t & 1;
        f2 v4 = 0.25f * (shfl_f2(v3, (2*y4)*4 + 2*x4)     + shfl_f2(v3, (2*y4)*4 + 2*x4 + 1) +
                         shfl_f2(v3, (2*y4+1)*4 + 2*x4)   + shfl_f2(v3, (2*y4+1)*4 + 2*x4 + 1));
        if (t < 4) {
            pyrP[PYR_OFF_L4 + ((ty0 >> 4) + y4) * 32 + (tx0 >> 4) + x4] = v4.x;
            pyrT[PYR_OFF_L4 + ((ty0 >> 4) + y4) * 32 + (tx0 >> 4) + x4] = v4.y;
        }
    }

    // single combined reduction: l1, csum -> per-block slots (no atomics)
    int lane = t & 63;
    int wid  = t >> 6;
    #pragma unroll
    for (int o = 32; o >= 1; o >>= 1) {
        l1   += __shfl_down(l1, o, 64);
        csum += __shfl_down(csum, o, 64);
    }
    if (lane == 0) {
        red12[wid * 2 + 0] = l1;
        red12[wid * 2 + 1] = csum;
    }
    __syncthreads();                                            // B4
    if (t < 4) {
        float a0 = red12[t * 2 + 0];
        float a2 = red12[t * 2 + 1];
        #pragma unroll
        for (int o = 2; o >= 1; o >>= 1) {
            a0 += __shfl_down(a0, o, 64);
            a2 += __shfl_down(a2, o, 64);
        }
        if (t == 0) {
            labPart[b * 256 + bx] = a0;
            csPart[b * 256 + bx]  = a2;
        }
    }
}

// Tail: 728 blocks.
//   bx < 48           : hist partial reduce — 6 blocks/image, 64 words each
//   48 <= bx < 728    : SSIM levels 1-4 (85 per image)
// Last block (completion counter) runs the finish: tiny slot reductions + output math.
// Producers: plain slot stores + __threadfence before counter bump.
// Finisher: device-scope atomic loads (cross-XCD coherent).
__global__ void tail_kernel(const float* __restrict__ ppyr,
                            const float* __restrict__ tpyr,
                            const unsigned* __restrict__ histPart,
                            const float* __restrict__ labPart,
                            const float* __restrict__ csPart,
                            float* __restrict__ lvlS,
                            float* __restrict__ lvlC,
                            float* __restrict__ histL1p,
                            unsigned* __restrict__ counter,
                            float* __restrict__ out) {
    __shared__ f2 tls[36 * TST];
    __shared__ float red12[12];
    __shared__ int dLo[256];
    __shared__ int dHi[256];
    __shared__ double sh[48];
    __shared__ double wred[4];
    __shared__ unsigned sdone;
    int t = threadIdx.x;
    int bx = blockIdx.x;

    if (bx < 48) {
        int b  = bx / 6;                       // image
        int w  = (bx % 6) * 64 + (t & 63);     // packed word within image
        int ck = t >> 6;                       // tile chunk 0..3 (64 tiles each)
        const unsigned* p = histPart + (size_t)b * 256 * 768 + (size_t)(ck * 64) * 768;
        unsigned sPlo = 0, sPhi = 0, sTlo = 0, sThi = 0;
        #pragma unroll 8
        for (int i = 0; i < 64; ++i) {
            unsigned wP = p[(size_t)i * 768 + w];          // lanes contiguous
            unsigned wT = p[(size_t)i * 768 + 384 + w];
            sPlo += wP & 0xFFFFu;  sPhi += wP >> 16;
            sTlo += wT & 0xFFFFu;  sThi += wT >> 16;
        }
        dLo[t] = (int)sPlo - (int)sTlo;        // exact signed partial diffs
        dHi[t] = (int)sPhi - (int)sThi;
        __syncthreads();
        if (t < 64) {                          // wave 0: combine 4 chunks per word
            int lo = dLo[t] + dLo[t + 64] + dLo[t + 128] + dLo[t + 192];
            int hi = dHi[t] + dHi[t + 64] + dHi[t + 128] + dHi[t + 192];
            float val = fabsf((float)lo) + fabsf((float)hi);   // exact: |.| < 2^24
            #pragma unroll
            for (int o = 32; o >= 1; o >>= 1) val += __shfl_down(val, o, 64);
            if (t == 0) histL1p[bx] = val;     // slot write
        }
    } else {
        int cb = bx - 48;
        int b = cb / 85;
        int sub = cb - b * 85;
        int lvl, pblk;
        if (sub < 64)      { lvl = 1; pblk = sub; }
        else if (sub < 80) { lvl = 2; pblk = sub - 64; }
        else if (sub < 84) { lvl = 3; pblk = sub - 80; }
        else               { lvl = 4; pblk = 0; }

        const int offs[5] = {0, PYR_OFF_L1, PYR_OFF_L2, PYR_OFF_L3, PYR_OFF_L4};
        int w = 512 >> lvl;
        const float* i1 = ppyr + (size_t)b * PYR_PER_IMG + offs[lvl];
        const float* i2 = tpyr + (size_t)b * PYR_PER_IMG + offs[lvl];

        int tprShift = 4 - lvl;
        int ty0 = (pblk >> tprShift) << 5;
        int tx0 = (pblk & ((1 << tprShift) - 1)) << 5;

        for (int i = t; i < 36 * 36; i += 256) {
            int r = i / 36, c = i % 36;
            int gy = ty0 - 2 + r;
            int gx = tx0 - 2 + c;
            bool ok = ((unsigned)gy < (unsigned)w) && ((unsigned)gx < (unsigned)w);
            int gi = gy * w + gx;
            tls[r * TST + c] = ok ? mkf2(i1[gi], i2[gi]) : mkf2(0.f, 0.f);
        }
        __syncthreads();

        float ssum, csum;
        conv_ssim<true>(tls, t, ssum, csum);

        int lane = t & 63;
        int wid  = t >> 6;
        #pragma unroll
        for (int o = 32; o >= 1; o >>= 1) {
            ssum += __shfl_down(ssum, o, 64);
            csum += __shfl_down(csum, o, 64);
        }
        if (lane == 0) {
            red12[wid * 2 + 0] = ssum;
            red12[wid * 2 + 1] = csum;
        }
        __syncthreads();
        if (t < 4) {
            float a1 = red12[t * 2 + 0];
            float a2 = red12[t * 2 + 1];
            #pragma unroll
            for (int o = 2; o >= 1; o >>= 1) {
                a1 += __shfl_down(a1, o, 64);
                a2 += __shfl_down(a2, o, 64);
            }
            if (t == 0) {
                lvlS[cb] = a1;                 // slot writes
                lvlC[cb] = a2;
            }
        }
    }

    // ---- completion: last of 728 blocks runs the finish ----
    __syncthreads();
    if (t == 0) {
        __threadfence();                       // make this block's slot writes device-visible
        sdone = atomicAdd(counter, 1u);
    }
    __syncthreads();
    if (sdone != 727u) return;

    // ======== finish (one block, all 256 threads, coherent loads) ========
    // sh layout (doubles): [0,8) cs lvl0 per image; [8,16) cs lvl1; [16,24) cs lvl2;
    //                      [24,32) cs lvl3; [32,40) ssim lvl4; [40,48) hist per image
    {
        int b = t >> 5, k = t & 31;            // per-image lvl0 cs: 32 lanes x 8 slots
        double s = 0.0;
        #pragma unroll
        for (int j = 0; j < 8; ++j) s += (double)aload(&csPart[b * 256 + k + 32 * j]);
        #pragma unroll
        for (int o = 16; o >= 1; o >>= 1) s += __shfl_down(s, o, 32);
        if (k == 0) sh[b] = s;
    }
    {
        double s = 0.0;                        // lab total over all 2048 slots
        #pragma unroll
        for (int j = 0; j < 8; ++j) s += (double)aload(&labPart[t + 256 * j]);
        #pragma unroll
        for (int o = 32; o >= 1; o >>= 1) s += __shfl_down(s, o, 64);
        if ((t & 63) == 0) wred[t >> 6] = s;
    }
    if (t < 32) {                              // level sums
        int b = t >> 2, q = t & 3;
        const int lo[4] = {0, 64, 80, 84};
        const int hi[4] = {64, 80, 84, 85};
        const float* src = (q == 3) ? lvlS : lvlC;
        double s = 0.0;
        for (int i = lo[q]; i < hi[q]; ++i) s += (double)aload(&src[b * 85 + i]);
        sh[8 + q * 8 + b] = s;
    }
    if (t < 8) {                               // hist per image: 6 slots each
        double s = 0.0;
        #pragma unroll
        for (int j = 0; j < 6; ++j) s += (double)aload(&histL1p[t * 6 + j]);
        sh[40 + t] = s;
    }
    __syncthreads();

    if (t < 8) {
        const float msw[5]  = {0.0448f, 0.2856f, 0.3001f, 0.2363f, 0.1333f};
        const float npix[5] = {(float)HW, (float)(HW/4), (float)(HW/16),
                               (float)(HW/64), (float)(HW/256)};
        int b = t;
        float l1 = (float)(sh[40 + b] / (double)(3 * NBINS));
        float wgt = __builtin_amdgcn_exp2f((float)(b - B));   // 2^(b-8), exact
        float histc = wgt * (l1 + 1.0f);
        float ms = 1.0f;
        float cs0 = (float)(sh[b] / (double)npix[0]);
        ms *= fastpow((cs0 + 1.0f) * 0.5f, msw[0]);
        #pragma unroll
        for (int l = 1; l <= 3; ++l) {
            float cs = (float)(sh[l * 8 + b] / (double)npix[l]);
            ms *= fastpow((cs + 1.0f) * 0.5f, msw[l]);
        }
        float sm = (float)(sh[32 + b] / (double)npix[4]);
        ms *= fastpow((sm + 1.0f) * 0.5f, msw[4]);
        float lossc = 1.0f - ms;
        #pragma unroll
        for (int o = 4; o >= 1; o >>= 1) {
            histc += __shfl_down(histc, o, 64);
            lossc += __shfl_down(lossc, o, 64);
        }
        if (t == 0) {
            double labSum = wred[0] + wred[1] + wred[2] + wred[3];
            float scaler = (float)HW / 20.0f;
            float hist_loss = histc / (float)B / scaler;
            float lab_l1 = (float)(labSum / (double)((size_t)B * 3 * HW));
            out[0] = lab_l1 + hist_loss;
            out[1] = lossc / (float)B;
        }
    }
}

extern "C" void kernel_launch(void* const* d_in, const int* in_sizes, int n_in,
                              void* d_out, int out_size, void* d_ws, size_t ws_size,
                              hipStream_t stream) {
    const float* pred = (const float*)d_in[1];
    const float* tgt  = (const float*)d_in[2];
    float* ws_f = (float*)d_ws;

    float* ppyr     = ws_f + OFF_PPYR;
    float* tpyr     = ws_f + OFF_TPYR;
    unsigned* histPart = (unsigned*)(ws_f + OFF_HISTPART);
    float* labPart  = ws_f + OFF_LABPART;
    float* csPart   = ws_f + OFF_CSP;
    float* lvlS     = ws_f + OFF_LVLS;
    float* lvlC     = ws_f + OFF_LVLC;
    float* histL1p  = ws_f + OFF_HISTL1;
    unsigned* counter = (unsigned*)(ws_f + OFF_CNT);
    float* out = (float*)d_out;

    // no memset: counter is zeroed by lab_ssim0_kernel; all slots fully rewritten

    lab_ssim0_kernel<<<dim3(256, B), 256, 0, stream>>>(pred, tgt, histPart, labPart,
                                                       csPart, ppyr, tpyr, counter);

    tail_kernel<<<728, 256, 0, stream>>>(ppyr, tpyr, histPart, labPart, csPart,
                                         lvlS, lvlC, histL1p, counter, out);
}

// Round 5
// 129.504 us; speedup vs baseline: 1.1584x; 1.1105x over previous
//
#include <hip/hip_runtime.h>
#include <math.h>

#define B 8
#define IMH 512
#define IMW 512
#define HW (IMH*IMW)
#define NBINS 256

// pyramid per-image: levels 1..4 (256^2, 128^2, 64^2, 32^2)
#define PYR_PER_IMG (65536 + 16384 + 4096 + 1024)   // 87040
#define PYR_OFF_L1 0
#define PYR_OFF_L2 65536
#define PYR_OFF_L3 81920
#define PYR_OFF_L4 86016

// workspace float-index offsets (all per-block slot arrays, NO atomics anywhere)
#define OFF_PPYR 0
#define OFF_TPYR (B*PYR_PER_IMG)
#define OFF_HISTPART (2*B*PYR_PER_IMG)              // u32: B*256*768 (u16-packed bins)
#define OFF_LABPART  (OFF_HISTPART + B*256*768)     // float: B*256
#define OFF_CSP      (OFF_LABPART + B*256)          // float: B*256 (lvl0 cs partials)
#define OFF_LVLS     (OFF_CSP + B*256)              // float: B*85  (lvl1-4 ssim partials)
#define OFF_LVLC     (OFF_LVLS + B*85)              // float: B*85  (lvl1-4 cs partials)
#define OFF_HISTL1   (OFF_LVLC + B*85)              // float: 48    (hist-diff partials)

typedef float f2 __attribute__((ext_vector_type(2)));

__device__ __forceinline__ f2 mkf2(float a, float b) { f2 r; r.x = a; r.y = b; return r; }
__device__ __forceinline__ f2 shfl_down_f2(f2 v, int d) {
    return mkf2(__shfl_down(v.x, d, 64), __shfl_down(v.y, d, 64));
}
__device__ __forceinline__ f2 shfl_f2(f2 v, int src) {
    return mkf2(__shfl(v.x, src, 64), __shfl(v.y, src, 64));
}
__device__ __forceinline__ f2 clamp01_f2(f2 a) {
    a.x = fminf(fmaxf(a.x, 0.0f), 1.0f);
    a.y = fminf(fmaxf(a.y, 0.0f), 1.0f);
    return a;
}

// native exp2/log2 (v_exp_f32 / v_log_f32, <=1 ulp). x must be > 0.
__device__ __forceinline__ float fastpow(float x, float y) {
    return __builtin_amdgcn_exp2f(y * __builtin_amdgcn_logf(x));
}

// packed rgb2lab: component .x = pred, .y = tgt.
__device__ __forceinline__ void rgb2lab_pk(f2 r, f2 g, f2 b, f2 lab[3]) {
    f2 v[3] = {r, g, b};
    f2 lin[3];
    #pragma unroll
    for (int c = 0; c < 3; ++c) {
        f2 x = v[c];
        float hx = fastpow((fmaxf(x.x, 1e-4f) + 0.055f) * (float)(1.0/1.055), 2.4f);
        float hy = fastpow((fmaxf(x.y, 1e-4f) + 0.055f) * (float)(1.0/1.055), 2.4f);
        lin[c].x = (x.x <= 0.04045f) ? x.x * (float)(1.0/12.92) : hx;
        lin[c].y = (x.y <= 0.04045f) ? x.y * (float)(1.0/12.92) : hy;
    }
    f2 X = 0.412453f*lin[0] + 0.357580f*lin[1] + 0.180423f*lin[2];
    f2 Y = 0.212671f*lin[0] + 0.715160f*lin[1] + 0.072169f*lin[2];
    f2 Z = 0.019334f*lin[0] + 0.119193f*lin[1] + 0.950227f*lin[2];
    X = X * (float)(1.0/0.950456);
    Z = Z * (float)(1.0/1.088754);
    const float eps3   = (float)((6.0/29.0)*(6.0/29.0)*(6.0/29.0));
    const float rd3e2  = (float)(1.0/(3.0*(6.0/29.0)*(6.0/29.0)));
    const float c429   = (float)(4.0/29.0);
    f2 xyz[3] = {X, Y, Z};
    f2 f[3];
    #pragma unroll
    for (int c = 0; c < 3; ++c) {
        float ax = xyz[c].x, ay = xyz[c].y;
        f[c].x = (ax <= eps3) ? (ax * rd3e2 + c429) : fastpow(fmaxf(ax, 1e-4f), (float)(1.0/3.0));
        f[c].y = (ay <= eps3) ? (ay * rd3e2 + c429) : fastpow(fmaxf(ay, 1e-4f), (float)(1.0/3.0));
    }
    f2 L  = 116.0f*f[1] - 16.0f;
    f2 A  = 500.0f*f[0] - 500.0f*f[1];
    f2 Bc = 200.0f*f[1] - 200.0f*f[2];
    lab[0] = L * 0.01f;
    lab[1] = (A * (float)(1.0/110.0) + 1.0f) * 0.5f;
    lab[2] = (Bc * (float)(1.0/110.0) + 1.0f) * 0.5f;
}

#define TST 37   // LDS row stride for 36-wide tiles

// packed separable 5x5 Gaussian SSIM over a 36x36 f2 tile ({pred,tgt} interleaved).
// v_rcp_f32 instead of precise div (rel err ~1e-7, threshold 7e-3).
// WANT_S=false skips the ssim-map sum (only mcs[0..3] and mssim[4] reach the output).
template<bool WANT_S>
__device__ __forceinline__ void conv_ssim(const f2* tile, int t, float& ssum, float& csum) {
    double gd[5]; double gs = 0.0;
    #pragma unroll
    for (int i = 0; i < 5; ++i) { gd[i] = exp(-(double)((i-2)*(i-2)) / 4.5); gs += gd[i]; }
    float gw[5];
    #pragma unroll
    for (int i = 0; i < 5; ++i) gw[i] = (float)(gd[i] / gs);

    int lx = t & 31;
    int yg = t >> 5;

    f2 rA[8], rB[8];     // {m1,m2}, {m11,m22}
    float r12[8];
    #pragma unroll
    for (int k = 0; k < 8; ++k) {
        int row = yg * 4 + k;
        const f2* p = &tile[row * TST + lx];
        f2 sA = {0.f, 0.f}, sB = {0.f, 0.f};
        float s12 = 0.f;
        #pragma unroll
        for (int dx = 0; dx < 5; ++dx) {
            f2 av = p[dx];
            float wv = gw[dx];
            sA += wv * av;
            f2 sq = av * av;
            sB += wv * sq;
            s12 = fmaf(wv, av.x * av.y, s12);
        }
        rA[k] = sA; rB[k] = sB; r12[k] = s12;
    }

    const float C1 = (float)(0.01 * 0.01);
    const float C2 = (float)(0.03 * 0.03);
    if constexpr (WANT_S) ssum = 0.f;
    csum = 0.f;
    #pragma unroll
    for (int j = 0; j < 4; ++j) {
        f2 mA = {0.f, 0.f}, mB = {0.f, 0.f};
        float m12 = 0.f;
        #pragma unroll
        for (int k = 0; k < 5; ++k) {
            float wv = gw[k];
            mA += wv * rA[j + k];
            mB += wv * rB[j + k];
            m12 = fmaf(wv, r12[j + k], m12);
        }
        float m1 = mA.x, m2 = mA.y;
        float v1  = mB.x - m1 * m1;
        float v2  = mB.y - m2 * m2;
        float v12 = m12 - m1 * m2;
        float n12 = 2.0f * v12 + C2;
        float rd2 = __builtin_amdgcn_rcpf(v1 + v2 + C2);
        csum = fmaf(n12, rd2, csum);
        if constexpr (WANT_S) {
            float rd1 = __builtin_amdgcn_rcpf(m1*m1 + m2*m2 + C1);
            ssum += (2.0f*m1*m2 + C1) * n12 * rd1 * rd2;
        }
    }
}

__device__ __forceinline__ void halo_coords(int h, int& hr, int& hc) {
    if (h < 72)       { hr = h / 36;            hc = h % 36; }
    else if (h < 144) { int u = h - 72;  hr = 34 + u / 36; hc = u % 36; }
    else              { int u = h - 144; hr = 2 + (u >> 2); int q = u & 3; hc = (q < 2) ? q : 32 + q; }
}

// Fused: LAB + hist partial + lvl0 SSIM-cs (halo recompute, prefetched) + full pyramid.
// One block = one 32x32 tile. grid (256, B) x 256; 4 px/thread.  [r2-verified structure]
// r5 changes vs r2: (1) global loads issued BEFORE lhist zero + B1 (overlap HBM latency
// with LDS zeroing/barrier); (2) interior ls stores batched after the rgb2lab loop
// (contiguous 32B -> wide ds_write).
__global__ void lab_ssim0_kernel(const float* __restrict__ pred,
                                 const float* __restrict__ tgt,
                                 unsigned* __restrict__ histPart,
                                 float* __restrict__ labPart,
                                 float* __restrict__ csPart,
                                 float* __restrict__ ppyr,
                                 float* __restrict__ tpyr) {
    __shared__ f2 ls[36 * TST];          // packed {Lp, Lt} halo tile
    __shared__ unsigned lhist[6 * NBINS];
    __shared__ f2 s1[16 * 16];           // packed L1
    __shared__ float red12[12];

    int t  = threadIdx.x;
    int b  = blockIdx.y;
    int bx = blockIdx.x;

    // XCD-aware swizzle: consecutive dispatch ids -> disjoint 2-tile-row strips
    int tile = ((bx & 7) << 5) | (bx >> 3);
    int tx0 = (tile & 15) << 5;
    int ty0 = (tile >> 4) << 5;
    int r   = t >> 3;            // row within tile (0..31)
    int c4  = (t & 7) << 2;      // col within tile (0,4,..,28)
    int gy  = ty0 + r;

    const float* pimg = pred + (size_t)b * 3 * HW;
    const float* timg = tgt  + (size_t)b * 3 * HW;
    size_t ibase = (size_t)gy * IMW + tx0 + c4;

    // ---- issue ALL loads up front (interior 6x float4 + halo px t's 6 scalars) ----
    float prA[4], pgA[4], pbA[4], trA[4], tgA[4], tbA[4];
    *(float4*)&prA[0] = *(const float4*)(pimg + ibase);
    *(float4*)&pgA[0] = *(const float4*)(pimg + ibase + HW);
    *(float4*)&pbA[0] = *(const float4*)(pimg + ibase + 2*HW);
    *(float4*)&trA[0] = *(const float4*)(timg + ibase);
    *(float4*)&tgA[0] = *(const float4*)(timg + ibase + HW);
    *(float4*)&tbA[0] = *(const float4*)(timg + ibase + 2*HW);

    int hr0, hc0;
    halo_coords(t, hr0, hc0);
    int hy0 = ty0 - 2 + hr0;
    int hx0 = tx0 - 2 + hc0;
    bool hv0 = ((unsigned)hy0 < 512u) && ((unsigned)hx0 < 512u);
    size_t ho = hv0 ? ((size_t)hy0 * IMW + hx0) : 0;   // clamped addr, masked later
    float h_pr = pimg[ho], h_pg = pimg[ho + HW], h_pb = pimg[ho + 2*HW];
    float h_tr = timg[ho], h_tg = timg[ho + HW], h_tb = timg[ho + 2*HW];

    // ---- zero hist LDS while loads are in flight ----
    for (int i = t; i < 6 * NBINS; i += 256) lhist[i] = 0;
    __syncthreads();                                            // B1

    // ---- interior compute (halo loads in flight) ----
    float l1 = 0.0f;
    f2 pL[4];
    #pragma unroll
    for (int k = 0; k < 4; ++k) {
        f2 lab[3];
        rgb2lab_pk(mkf2(prA[k], trA[k]), mkf2(pgA[k], tgA[k]), mkf2(pbA[k], tbA[k]), lab);
        #pragma unroll
        for (int c = 0; c < 3; ++c) {
            f2 lc = clamp01_f2(lab[c]);
            l1 += fabsf(lc.x - lc.y);
            int ip = min(max((int)floorf(lc.x * (float)NBINS), 0), NBINS - 1);
            int it = min(max((int)floorf(lc.y * (float)NBINS), 0), NBINS - 1);
            atomicAdd(&lhist[c * NBINS + ip], 1u);
            atomicAdd(&lhist[(3 + c) * NBINS + it], 1u);
            if (c == 0) pL[k] = lc;
        }
    }
    // batched contiguous LDS stores (32B, 16B-aligned -> wide ds_write)
    {
        f2* dst = &ls[(r + 2) * TST + (c4 + 2)];
        dst[0] = pL[0]; dst[1] = pL[1]; dst[2] = pL[2]; dst[3] = pL[3];
    }

    // ---- halo px t (prefetched) ----
    {
        f2 lab[3];
        rgb2lab_pk(mkf2(h_pr, h_tr), mkf2(h_pg, h_tg), mkf2(h_pb, h_tb), lab);
        f2 Lv = hv0 ? clamp01_f2(lab[0]) : mkf2(0.f, 0.f);
        ls[hr0 * TST + hc0] = Lv;
    }
    // ---- remaining 16 halo px (t < 16) ----
    if (t < 16) {
        int hr, hc;
        halo_coords(256 + t, hr, hc);
        int hy = ty0 - 2 + hr;
        int hx = tx0 - 2 + hc;
        f2 Lv = {0.f, 0.f};
        if ((unsigned)hy < 512u && (unsigned)hx < 512u) {
            size_t o = (size_t)hy * IMW + hx;
            f2 lab[3];
            rgb2lab_pk(mkf2(pimg[o], timg[o]),
                       mkf2(pimg[o + HW], timg[o + HW]),
                       mkf2(pimg[o + 2*HW], timg[o + 2*HW]), lab);
            Lv = clamp01_f2(lab[0]);
        }
        ls[hr * TST + hc] = Lv;
    }
    __syncthreads();                                            // B2

    // non-atomic per-block histogram partial, u16-packed two bins per u32
    unsigned* hp = histPart + ((size_t)b * 256 + bx) * 768;
    for (int i = t; i < 768; i += 256)
        hp[i] = (lhist[2*i] & 0xFFFFu) | (lhist[2*i + 1] << 16);

    // pyramid L1 from registers (shuffles), packed
    float* pyrP = ppyr + (size_t)b * PYR_PER_IMG;
    float* pyrT = tpyr + (size_t)b * PYR_PER_IMG;
    f2 ph0 = pL[0] + pL[1], ph1 = pL[2] + pL[3];
    f2 ph0b = shfl_down_f2(ph0, 8);
    f2 ph1b = shfl_down_f2(ph1, 8);
    if ((t & 8) == 0) {                 // even row r
        int y1 = r >> 1;
        int x1 = (t & 7) << 1;
        f2 v0 = 0.25f * (ph0 + ph0b);
        f2 v1 = 0.25f * (ph1 + ph1b);
        s1[y1 * 16 + x1]     = v0;
        s1[y1 * 16 + x1 + 1] = v1;
        int g1 = ((ty0 >> 1) + y1) * 256 + (tx0 >> 1) + x1;
        *(float2*)&pyrP[PYR_OFF_L1 + g1] = make_float2(v0.x, v1.x);
        *(float2*)&pyrT[PYR_OFF_L1 + g1] = make_float2(v0.y, v1.y);
    }
    __syncthreads();                                            // B3

    // lvl0 SSIM-cs from packed LDS tile (ssim-map sum not needed at lvl0)
    float sdummy, csum;
    conv_ssim<false>(ls, t, sdummy, csum);

    // pyramid L2-L4: wave 0 only (shuffle cascade, no barriers)
    if (t < 64) {
        int y2 = t >> 3, x2 = t & 7;
        const f2* s = &s1[(2*y2) * 16 + 2*x2];
        f2 v2 = 0.25f * (s[0] + s[1] + s[16] + s[17]);
        pyrP[PYR_OFF_L2 + ((ty0 >> 2) + y2) * 128 + (tx0 >> 2) + x2] = v2.x;
        pyrT[PYR_OFF_L2 + ((ty0 >> 2) + y2) * 128 + (tx0 >> 2) + x2] = v2.y;

        int y3 = (t >> 2) & 3, x3 = t & 3;
        f2 v3 = 0.25f * (shfl_f2(v2, (2*y3)*8 + 2*x3)     + shfl_f2(v2, (2*y3)*8 + 2*x3 + 1) +
                         shfl_f2(v2, (2*y3+1)*8 + 2*x3)   + shfl_f2(v2, (2*y3+1)*8 + 2*x3 + 1));
        if (t < 16) {
            pyrP[PYR_OFF_L3 + ((ty0 >> 3) + y3) * 64 + (tx0 >> 3) + x3] = v3.x;
            pyrT[PYR_OFF_L3 + ((ty0 >> 3) + y3) * 64 + (tx0 >> 3) + x3] = v3.y;
        }
        int y4 = (t >> 1) & 1, x4 = t & 1;
        f2 v4 = 0.25f * (shfl_f2(v3, (2*y4)*4 + 2*x4)     + shfl_f2(v3, (2*y4)*4 + 2*x4 + 1) +
                         shfl_f2(v3, (2*y4+1)*4 + 2*x4)   + shfl_f2(v3, (2*y4+1)*4 + 2*x4 + 1));
        if (t < 4) {
            pyrP[PYR_OFF_L4 + ((ty0 >> 4) + y4) * 32 + (tx0 >> 4) + x4] = v4.x;
            pyrT[PYR_OFF_L4 + ((ty0 >> 4) + y4) * 32 + (tx0 >> 4) + x4] = v4.y;
        }
    }

    // single combined reduction: l1, csum -> per-block slots (no atomics)
    int lane = t & 63;
    int wid  = t >> 6;
    #pragma unroll
    for (int o = 32; o >= 1; o >>= 1) {
        l1   += __shfl_down(l1, o, 64);
        csum += __shfl_down(csum, o, 64);
    }
    if (lane == 0) {
        red12[wid * 2 + 0] = l1;
        red12[wid * 2 + 1] = csum;
    }
    __syncthreads();                                            // B4
    if (t < 4) {
        float a0 = red12[t * 2 + 0];
        float a2 = red12[t * 2 + 1];
        #pragma unroll
        for (int o = 2; o >= 1; o >>= 1) {
            a0 += __shfl_down(a0, o, 64);
            a2 += __shfl_down(a2, o, 64);
        }
        if (t == 0) {
            labPart[b * 256 + bx] = a0;
            csPart[b * 256 + bx]  = a2;
        }
    }
}

// Tail: 728 blocks, NO atomics / fences / counters — per-block slot writes only.
//   bx < 48           : hist partial reduce — 6 blocks/image, 64 words each
//   48 <= bx < 728    : SSIM levels 1-4 (85 per image)
__global__ void tail_kernel(const float* __restrict__ ppyr,
                            const float* __restrict__ tpyr,
                            const unsigned* __restrict__ histPart,
                            float* __restrict__ lvlS,
                            float* __restrict__ lvlC,
                            float* __restrict__ histL1p) {
    __shared__ f2 tls[36 * TST];
    __shared__ float red12[12];
    __shared__ int dLo[256];
    __shared__ int dHi[256];
    int t = threadIdx.x;
    int bx = blockIdx.x;

    if (bx < 48) {
        int b  = bx / 6;                       // image
        int w  = (bx % 6) * 64 + (t & 63);     // packed word within image
        int ck = t >> 6;                       // tile chunk 0..3 (64 tiles each)
        const unsigned* p = histPart + (size_t)b * 256 * 768 + (size_t)(ck * 64) * 768;
        unsigned sPlo = 0, sPhi = 0, sTlo = 0, sThi = 0;
        #pragma unroll 8
        for (int i = 0; i < 64; ++i) {
            unsigned wP = p[(size_t)i * 768 + w];          // lanes contiguous
            unsigned wT = p[(size_t)i * 768 + 384 + w];
            sPlo += wP & 0xFFFFu;  sPhi += wP >> 16;
            sTlo += wT & 0xFFFFu;  sThi += wT >> 16;
        }
        dLo[t] = (int)sPlo - (int)sTlo;        // exact signed partial diffs
        dHi[t] = (int)sPhi - (int)sThi;
        __syncthreads();
        if (t < 64) {                          // wave 0: combine 4 chunks per word
            int lo = dLo[t] + dLo[t + 64] + dLo[t + 128] + dLo[t + 192];
            int hi = dHi[t] + dHi[t + 64] + dHi[t + 128] + dHi[t + 192];
            float val = fabsf((float)lo) + fabsf((float)hi);   // exact: |.| < 2^24
            #pragma unroll
            for (int o = 32; o >= 1; o >>= 1) val += __shfl_down(val, o, 64);
            if (t == 0) histL1p[bx] = val;     // slot write, no atomic
        }
    } else {
        int cb = bx - 48;
        int b = cb / 85;
        int sub = cb - b * 85;
        int lvl, pblk;
        if (sub < 64)      { lvl = 1; pblk = sub; }
        else if (sub < 80) { lvl = 2; pblk = sub - 64; }
        else if (sub < 84) { lvl = 3; pblk = sub - 80; }
        else               { lvl = 4; pblk = 0; }

        const int offs[5] = {0, PYR_OFF_L1, PYR_OFF_L2, PYR_OFF_L3, PYR_OFF_L4};
        int w = 512 >> lvl;
        const float* i1 = ppyr + (size_t)b * PYR_PER_IMG + offs[lvl];
        const float* i2 = tpyr + (size_t)b * PYR_PER_IMG + offs[lvl];

        int tprShift = 4 - lvl;
        int ty0 = (pblk >> tprShift) << 5;
        int tx0 = (pblk & ((1 << tprShift) - 1)) << 5;

        for (int i = t; i < 36 * 36; i += 256) {
            int r = i / 36, c = i % 36;
            int gy = ty0 - 2 + r;
            int gx = tx0 - 2 + c;
            bool ok = ((unsigned)gy < (unsigned)w) && ((unsigned)gx < (unsigned)w);
            int gi = gy * w + gx;
            tls[r * TST + c] = ok ? mkf2(i1[gi], i2[gi]) : mkf2(0.f, 0.f);
        }
        __syncthreads();

        float ssum, csum;
        conv_ssim<true>(tls, t, ssum, csum);

        int lane = t & 63;
        int wid  = t >> 6;
        #pragma unroll
        for (int o = 32; o >= 1; o >>= 1) {
            ssum += __shfl_down(ssum, o, 64);
            csum += __shfl_down(csum, o, 64);
        }
        if (lane == 0) {
            red12[wid * 2 + 0] = ssum;
            red12[wid * 2 + 1] = csum;
        }
        __syncthreads();
        if (t < 4) {
            float a1 = red12[t * 2 + 0];
            float a2 = red12[t * 2 + 1];
            #pragma unroll
            for (int o = 2; o >= 1; o >>= 1) {
                a1 += __shfl_down(a1, o, 64);
                a2 += __shfl_down(a2, o, 64);
            }
            if (t == 0) {
                lvlS[cb] = a1;                 // slot writes, no atomics
                lvlC[cb] = a2;
            }
        }
    }
}

// Final: ONE block does all the tiny reductions + output math.
__global__ void final_kernel(const float* __restrict__ labPart,
                             const float* __restrict__ csPart,
                             const float* __restrict__ lvlS,
                             const float* __restrict__ lvlC,
                             const float* __restrict__ histL1p,
                             float* __restrict__ out) {
    // sh layout (doubles): [0,8) cs lvl0 per image; [8,16) cs lvl1; [16,24) cs lvl2;
    //                      [24,32) cs lvl3; [32,40) ssim lvl4; [40,48) hist per image
    __shared__ double sh[48];
    __shared__ double wred[4];
    int t = threadIdx.x;

    // per-image lvl0 cs: 32 lanes per image, 8 slots each
    {
        int b = t >> 5, k = t & 31;
        double s = 0.0;
        #pragma unroll
        for (int j = 0; j < 8; ++j) s += (double)csPart[b * 256 + k + 32 * j];
        #pragma unroll
        for (int o = 16; o >= 1; o >>= 1) s += __shfl_down(s, o, 32);
        if (k == 0) sh[b] = s;
    }
    // lab total over all 2048 slots
    {
        double s = 0.0;
        #pragma unroll
        for (int j = 0; j < 8; ++j) s += (double)labPart[t + 256 * j];
        #pragma unroll
        for (int o = 32; o >= 1; o >>= 1) s += __shfl_down(s, o, 64);
        if ((t & 63) == 0) wred[t >> 6] = s;
    }
    // level sums: t<32 -> b=t>>2, q=t&3; q=0..2: cs lvl(q+1); q=3: ssim lvl4
    if (t < 32) {
        int b = t >> 2, q = t & 3;
        const int lo[4] = {0, 64, 80, 84};
        const int hi[4] = {64, 80, 84, 85};
        const float* src = (q == 3) ? lvlS : lvlC;
        double s = 0.0;
        for (int i = lo[q]; i < hi[q]; ++i) s += (double)src[b * 85 + i];
        sh[8 + q * 8 + b] = s;
    }
    // hist per image: 6 slots each
    if (t < 8) {
        double s = 0.0;
        #pragma unroll
        for (int j = 0; j < 6; ++j) s += (double)histL1p[t * 6 + j];
        sh[40 + t] = s;
    }
    __syncthreads();

    if (t < 8) {
        const float msw[5]  = {0.0448f, 0.2856f, 0.3001f, 0.2363f, 0.1333f};
        const float npix[5] = {(float)HW, (float)(HW/4), (float)(HW/16),
                               (float)(HW/64), (float)(HW/256)};
        int b = t;
        float l1 = (float)(sh[40 + b] / (double)(3 * NBINS));
        float wgt = __builtin_amdgcn_exp2f((float)(b - B));   // 2^(b-8), exact
        float histc = wgt * (l1 + 1.0f);
        float ms = 1.0f;
        float cs0 = (float)(sh[b] / (double)npix[0]);
        ms *= fastpow((cs0 + 1.0f) * 0.5f, msw[0]);
        #pragma unroll
        for (int l = 1; l <= 3; ++l) {
            float cs = (float)(sh[l * 8 + b] / (double)npix[l]);
            ms *= fastpow((cs + 1.0f) * 0.5f, msw[l]);
        }
        float sm = (float)(sh[32 + b] / (double)npix[4]);
        ms *= fastpow((sm + 1.0f) * 0.5f, msw[4]);
        float lossc = 1.0f - ms;
        #pragma unroll
        for (int o = 4; o >= 1; o >>= 1) {
            histc += __shfl_down(histc, o, 64);
            lossc += __shfl_down(lossc, o, 64);
        }
        if (t == 0) {
            double labSum = wred[0] + wred[1] + wred[2] + wred[3];
            float scaler = (float)HW / 20.0f;
            float hist_loss = histc / (float)B / scaler;
            float lab_l1 = (float)(labSum / (double)((size_t)B * 3 * HW));
            out[0] = lab_l1 + hist_loss;
            out[1] = lossc / (float)B;
        }
    }
}

extern "C" void kernel_launch(void* const* d_in, const int* in_sizes, int n_in,
                              void* d_out, int out_size, void* d_ws, size_t ws_size,
                              hipStream_t stream) {
    const float* pred = (const float*)d_in[1];
    const float* tgt  = (const float*)d_in[2];
    float* ws_f = (float*)d_ws;

    float* ppyr     = ws_f + OFF_PPYR;
    float* tpyr     = ws_f + OFF_TPYR;
    unsigned* histPart = (unsigned*)(ws_f + OFF_HISTPART);
    float* labPart  = ws_f + OFF_LABPART;
    float* csPart   = ws_f + OFF_CSP;
    float* lvlS     = ws_f + OFF_LVLS;
    float* lvlC     = ws_f + OFF_LVLC;
    float* histL1p  = ws_f + OFF_HISTL1;
    float* out = (float*)d_out;

    // no memset needed: every workspace slot is fully rewritten before being read

    lab_ssim0_kernel<<<dim3(256, B), 256, 0, stream>>>(pred, tgt, histPart, labPart,
                                                       csPart, ppyr, tpyr);

    tail_kernel<<<728, 256, 0, stream>>>(ppyr, tpyr, histPart, lvlS, lvlC, histL1p);

    final_kernel<<<1, 256, 0, stream>>>(labPart, csPart, lvlS, lvlC, histL1p, out);
}